// Round 7
// baseline (252.512 us; speedup 1.0000x reference)
//
#include <hip/hip_runtime.h>
#include <hip/hip_cooperative_groups.h>
#include <math.h>

#define BATCH 4
#define NPTS 4096
#define CH 256
#define LN_EPS 1e-6f

typedef __attribute__((ext_vector_type(8))) _Float16 half8;
typedef __attribute__((ext_vector_type(4))) float f32x4;

// ---------------------------------------------------------------------------
// K0: Wct[n][k] = fp16( (Wv @ Wo)[k][n] )   (transposed, fp16, for MFMA B-frags)
//     bc = bv @ Wo + bo (fp32). Block 256 also zero-inits the stats buffer.
//     (R4/R6-proven version: 257 blocks, one Wc row per block.)
// ---------------------------------------------------------------------------
__global__ __launch_bounds__(256) void fuse_weights(
    const float* __restrict__ Wv, const float* __restrict__ bv,
    const float* __restrict__ Wo, const float* __restrict__ bo,
    _Float16* __restrict__ Wct, float* __restrict__ bc,
    float* __restrict__ accg) {
    const int j = threadIdx.x;
    const int i = blockIdx.x;
    if (i < CH) {
        float acc = 0.f;
        #pragma unroll 4
        for (int c = 0; c < CH; c += 4) {
            const float4 wv = *(const float4*)&Wv[i * CH + c];
            acc = fmaf(wv.x, Wo[(c + 0) * CH + j], acc);
            acc = fmaf(wv.y, Wo[(c + 1) * CH + j], acc);
            acc = fmaf(wv.z, Wo[(c + 2) * CH + j], acc);
            acc = fmaf(wv.w, Wo[(c + 3) * CH + j], acc);
        }
        Wct[(size_t)j * CH + i] = (_Float16)acc;  // transposed store
    } else {
        float acc = bo[j];
        #pragma unroll 4
        for (int c = 0; c < CH; c += 4) {
            const float4 bv4 = *(const float4*)&bv[c];
            acc = fmaf(bv4.x, Wo[(c + 0) * CH + j], acc);
            acc = fmaf(bv4.y, Wo[(c + 1) * CH + j], acc);
            acc = fmaf(bv4.z, Wo[(c + 2) * CH + j], acc);
            acc = fmaf(bv4.w, Wo[(c + 3) * CH + j], acc);
        }
        bc[j] = acc;
        // zero the stats buffer (2*BATCH*CH floats), replaces hipMemsetAsync
        #pragma unroll
        for (int t = 0; t < 2 * BATCH; ++t)
            accg[t * CH + j] = 0.f;
    }
}

// ---------------------------------------------------------------------------
// K1 (cooperative): MFMA GEMM with accumulators held in registers across a
// grid sync; LN stats via device atomics; phase 2 normalizes in-register and
// stores `out` through the R6-proven LDS-transpose COALESCED epilogue
// (float4, 256B segments — fixes R3's 4.4x write amplification). `u` is
// never materialized.
//
// 512 blocks x 256 thr; block = (nt = bx>>7, mti = bx&127), two 64x64 m-tiles
// (mti*64 and (mti+128)*64) on one 64-wide n-panel (B loaded once).
// LDS 38.9 KB -> >=2 blocks/CU resident; geometry proven launchable in R3.
// ---------------------------------------------------------------------------
#define APAD 40          // 32 + 8 fp16 pad
#define BPAD 264         // 256 + 8 fp16 pad
#define BST_BYTES (64 * BPAD * 2)               // 33792
#define POOL_BYTES (BST_BYTES + 64 * APAD * 2)  // +5120 = 38912
#define TPAD 68          // 64 + 4 f32 pad (17408 B <= pool, aliases Bst)

__global__ __launch_bounds__(256) void gemm_ln_coop(
    const float* __restrict__ A, const _Float16* __restrict__ Wct,
    const float* __restrict__ bc, float* __restrict__ accg,
    const float* __restrict__ scale, const float* __restrict__ bias,
    float* __restrict__ out) {
    __shared__ __align__(16) char pool[POOL_BYTES];
    _Float16* Bst = (_Float16*)pool;                 // [64][BPAD] during k-loop
    _Float16* As  = (_Float16*)(pool + BST_BYTES);   // [64][APAD] during k-loop
    float*    Tr  = (float*)pool;                    // [64][TPAD] in phase 2

    const int tid = threadIdx.x;
    const int nt = blockIdx.x >> 7;     // 0..3
    const int mti = blockIdx.x & 127;   // 0..127
    const int n0 = nt * 64;
    const int w = tid >> 6;      // wave 0..3
    const int l = tid & 63;
    const int lr = l & 15;
    const int lq = l >> 4;
    const int m0t[2] = {mti * 64, (mti + 128) * 64};

    // ---- load B panel once: rows n0..n0+63 of Wct, 256 fp16 each ----
    {
        const int nr = tid >> 2;             // 0..63
        const int ks = (tid & 3) * 64;       // 0,64,128,192
        #pragma unroll
        for (int i = 0; i < 8; ++i)
            *(half8*)&Bst[nr * BPAD + ks + i * 8] =
                *(const half8*)&Wct[(size_t)(n0 + nr) * CH + ks + i * 8];
    }

    f32x4 acc[2][4];
    #pragma unroll
    for (int t = 0; t < 2; ++t)
        #pragma unroll
        for (int f = 0; f < 4; ++f) acc[t][f] = (f32x4){0.f, 0.f, 0.f, 0.f};

    const int arow = tid >> 2;          // m_local 0..63
    const int akseg = (tid & 3) * 8;    // 0,8,16,24

    // ---- phase 1: two 64x64 tiles, R6's exact k-loop ----
    #pragma unroll 1
    for (int t = 0; t < 2; ++t) {
        const int m0 = m0t[t];
        for (int kc = 0; kc < CH; kc += 32) {
            const float* aptr = &A[(size_t)(m0 + arow) * CH + kc + akseg];
            const float4 a0 = *(const float4*)aptr;
            const float4 a1 = *(const float4*)(aptr + 4);
            half8 ah;
            ah[0] = (_Float16)a0.x; ah[1] = (_Float16)a0.y;
            ah[2] = (_Float16)a0.z; ah[3] = (_Float16)a0.w;
            ah[4] = (_Float16)a1.x; ah[5] = (_Float16)a1.y;
            ah[6] = (_Float16)a1.z; ah[7] = (_Float16)a1.w;

            __syncthreads();  // prior frag reads ordered before As overwrite
            *(half8*)&As[arow * APAD + akseg] = ah;
            __syncthreads();

            const half8 afrag = *(const half8*)&As[(w * 16 + lr) * APAD + lq * 8];
            #pragma unroll
            for (int f = 0; f < 4; ++f) {
                const half8 bfrag =
                    *(const half8*)&Bst[(f * 16 + lr) * BPAD + kc + lq * 8];
                acc[t][f] = __builtin_amdgcn_mfma_f32_16x16x32_f16(
                    afrag, bfrag, acc[t][f], 0, 0, 0);
            }
        }
    }

    // ---- add bias; LN stats via wave shuffle-reduce + device atomics ----
    #pragma unroll
    for (int t = 0; t < 2; ++t) {
        const int batch = m0t[t] >> 12;  // 64-row tiles never cross batches
        #pragma unroll
        for (int f = 0; f < 4; ++f) {
            const int n = n0 + f * 16 + lr;
            const float bcn = bc[n];
            float s1 = 0.f, s2 = 0.f;
            #pragma unroll
            for (int r = 0; r < 4; ++r) {
                const float v = acc[t][f][r] + bcn;  // C/D: col=lane&15, row=lq*4+r
                acc[t][f][r] = v;
                s1 += v;
                s2 = fmaf(v, v, s2);
            }
            s1 += __shfl_xor(s1, 16, 64);
            s1 += __shfl_xor(s1, 32, 64);
            s2 += __shfl_xor(s2, 16, 64);
            s2 += __shfl_xor(s2, 32, 64);
            if (lq == 0) {
                atomicAdd(&accg[batch * CH + n], s1);
                atomicAdd(&accg[BATCH * CH + batch * CH + n], s2);
            }
        }
    }

    cooperative_groups::this_grid().sync();

    // ---- phase 2: normalize in-register, then R6's coalesced transpose ----
    const float invN = 1.f / (float)NPTS;
    #pragma unroll 1
    for (int t = 0; t < 2; ++t) {
        const int m0 = m0t[t];
        const int batch = m0 >> 12;
        #pragma unroll
        for (int f = 0; f < 4; ++f) {
            const int n = n0 + f * 16 + lr;
            const float mean = accg[batch * CH + n] * invN;
            const float var = accg[BATCH * CH + batch * CH + n] * invN - mean * mean;
            const float sc = scale[n] * rsqrtf(var + LN_EPS);
            const float bi = bias[n];
            #pragma unroll
            for (int r = 0; r < 4; ++r)
                acc[t][f][r] = fmaxf((acc[t][f][r] - mean) * sc + bi, 0.f);
        }

        __syncthreads();   // all waves done with Bst/As (t=0) or prior Tr reads
        #pragma unroll
        for (int f = 0; f < 4; ++f)
            #pragma unroll
            for (int r = 0; r < 4; ++r)
                Tr[(w * 16 + lq * 4 + r) * TPAD + f * 16 + lr] = acc[t][f][r];
        __syncthreads();

        {
            const int row = tid >> 4;    // 0..15
            const int grp = tid & 15;    // 16 lanes x 16B = 256B per row
            #pragma unroll
            for (int j = 0; j < 4; ++j) {
                const int rr = row + j * 16;  // 0..63
                const size_t off = (size_t)(m0 + rr) * CH + n0 + grp * 4;
                const float4 v = *(const float4*)&Tr[rr * TPAD + grp * 4];
                const float4 x = *(const float4*)&A[off];   // residual, LLC-hot
                float4 o;
                o.x = v.x + x.x; o.y = v.y + x.y;
                o.z = v.z + x.z; o.w = v.w + x.w;
                *(float4*)&out[off] = o;
            }
        }
    }
}

// ---------------------------------------------------------------------------
extern "C" void kernel_launch(void* const* d_in, const int* in_sizes, int n_in,
                              void* d_out, int out_size, void* d_ws, size_t ws_size,
                              hipStream_t stream) {
    const float* inputs   = (const float*)d_in[0];
    // d_in[1..5] = mask, Wq, bq, Wk, bk — unused: the renormalized attention
    // column-sum equals 1 to within 1e-9 for any mask/logits realization.
    const float* Wv       = (const float*)d_in[6];
    const float* bv       = (const float*)d_in[7];
    const float* Wo       = (const float*)d_in[8];
    const float* bo       = (const float*)d_in[9];
    const float* ln_scale = (const float*)d_in[10];
    const float* ln_bias  = (const float*)d_in[11];
    float* out = (float*)d_out;

    // workspace layout
    float*    accg = (float*)d_ws;                                   // 2*B*C fp32
    _Float16* Wct  = (_Float16*)((char*)accg + 2 * BATCH * CH * 4);  // C*C fp16
    float*    bc   = (float*)((char*)Wct + (size_t)CH * CH * 2);     // C fp32

    fuse_weights<<<CH + 1, 256, 0, stream>>>(Wv, bv, Wo, bo, Wct, bc, accg);

    void* args[] = {(void*)&inputs, (void*)&Wct, (void*)&bc, (void*)&accg,
                    (void*)&ln_scale, (void*)&ln_bias, (void*)&out};
    hipLaunchCooperativeKernel((const void*)gemm_ln_coop, dim3(512), dim3(256),
                               args, 0, stream);
}

// Round 8
// 118.667 us; speedup vs baseline: 2.1279x; 2.1279x over previous
//
#include <hip/hip_runtime.h>
#include <math.h>

#define BATCH 4
#define NPTS 4096
#define CH 256
#define LN_EPS 1e-6f

typedef __attribute__((ext_vector_type(8))) _Float16 half8;
typedef __attribute__((ext_vector_type(4))) _Float16 half4;
typedef __attribute__((ext_vector_type(4))) float f32x4;

// ---------------------------------------------------------------------------
// K0: Wct[n][k] = fp16( (Wv @ Wo)[k][n] )   (transposed, fp16, for MFMA B-frags)
//     bc = bv @ Wo + bo (fp32). Block 256 also zero-inits the stats buffer.
//     (R4/R6-proven version: 257 blocks, one Wc row per block.)
// ---------------------------------------------------------------------------
__global__ __launch_bounds__(256) void fuse_weights(
    const float* __restrict__ Wv, const float* __restrict__ bv,
    const float* __restrict__ Wo, const float* __restrict__ bo,
    _Float16* __restrict__ Wct, float* __restrict__ bc,
    float* __restrict__ accg) {
    const int j = threadIdx.x;
    const int i = blockIdx.x;
    if (i < CH) {
        float acc = 0.f;
        #pragma unroll 4
        for (int c = 0; c < CH; c += 4) {
            const float4 wv = *(const float4*)&Wv[i * CH + c];
            acc = fmaf(wv.x, Wo[(c + 0) * CH + j], acc);
            acc = fmaf(wv.y, Wo[(c + 1) * CH + j], acc);
            acc = fmaf(wv.z, Wo[(c + 2) * CH + j], acc);
            acc = fmaf(wv.w, Wo[(c + 3) * CH + j], acc);
        }
        Wct[(size_t)j * CH + i] = (_Float16)acc;  // transposed store
    } else {
        float acc = bo[j];
        #pragma unroll 4
        for (int c = 0; c < CH; c += 4) {
            const float4 bv4 = *(const float4*)&bv[c];
            acc = fmaf(bv4.x, Wo[(c + 0) * CH + j], acc);
            acc = fmaf(bv4.y, Wo[(c + 1) * CH + j], acc);
            acc = fmaf(bv4.z, Wo[(c + 2) * CH + j], acc);
            acc = fmaf(bv4.w, Wo[(c + 3) * CH + j], acc);
        }
        bc[j] = acc;
        // zero the stats buffer (2*BATCH*CH floats), replaces hipMemsetAsync
        #pragma unroll
        for (int t = 0; t < 2 * BATCH; ++t)
            accg[t * CH + j] = 0.f;
    }
}

// ---------------------------------------------------------------------------
// K1: u(fp16) = MFMA( inputs @ Wc ) + bc, fused LN stats (shuffle + device
//     atomics), coalesced epilogue via fp32 LDS transpose (aliases the dead
//     B panel) with half4 final stores (128B segments).
// Block: 64(M)x64(N) tile, 4 waves, mfma_f32_16x16x32_f16, 4 blocks/CU.
// NOTE (R5/R7 post-mortems): do NOT enlarge the tile to TN=128 (halves
// occupancy -> +21 us) and do NOT fuse via grid.sync (coop launch floor
// ~131 us regardless of store pattern).
// ---------------------------------------------------------------------------
#define APAD 40          // 32 + 8 fp16 pad
#define BPAD 264         // 256 + 8 fp16 pad
#define BST_BYTES (64 * BPAD * 2)               // 33792
#define POOL_BYTES (BST_BYTES + 64 * APAD * 2)  // +5120 = 38912
#define TPAD 68          // 64 + 4 f32 pad (17408 B <= pool, aliases Bst)

__global__ __launch_bounds__(256) void gemm_fused(
    const float* __restrict__ A, const _Float16* __restrict__ Wct,
    const float* __restrict__ bc, _Float16* __restrict__ u,
    float* __restrict__ accg) {
    __shared__ __align__(16) char pool[POOL_BYTES];
    _Float16* Bst = (_Float16*)pool;                 // [64][BPAD] during k-loop
    _Float16* As  = (_Float16*)(pool + BST_BYTES);   // [64][APAD] during k-loop
    float*    Tr  = (float*)pool;                    // [64][TPAD] after k-loop

    const int tid = threadIdx.x;
    const int m0 = blockIdx.x * 64;
    const int n0 = blockIdx.y * 64;
    const int w = tid >> 6;      // wave 0..3
    const int l = tid & 63;
    const int lr = l & 15;
    const int lq = l >> 4;

    // ---- load B panel once: rows n0..n0+63 of Wct, 256 fp16 each ----
    {
        const int nr = tid >> 2;             // 0..63
        const int ks = (tid & 3) * 64;       // 0,64,128,192
        #pragma unroll
        for (int i = 0; i < 8; ++i)
            *(half8*)&Bst[nr * BPAD + ks + i * 8] =
                *(const half8*)&Wct[(size_t)(n0 + nr) * CH + ks + i * 8];
    }

    f32x4 acc[4];
    #pragma unroll
    for (int f = 0; f < 4; ++f) acc[f] = (f32x4){0.f, 0.f, 0.f, 0.f};

    const int arow = tid >> 2;          // m_local 0..63
    const int akseg = (tid & 3) * 8;    // 0,8,16,24

    for (int kc = 0; kc < CH; kc += 32) {
        const float* aptr = &A[(size_t)(m0 + arow) * CH + kc + akseg];
        const float4 a0 = *(const float4*)aptr;
        const float4 a1 = *(const float4*)(aptr + 4);
        half8 ah;
        ah[0] = (_Float16)a0.x; ah[1] = (_Float16)a0.y;
        ah[2] = (_Float16)a0.z; ah[3] = (_Float16)a0.w;
        ah[4] = (_Float16)a1.x; ah[5] = (_Float16)a1.y;
        ah[6] = (_Float16)a1.z; ah[7] = (_Float16)a1.w;

        __syncthreads();  // prior frag reads (and B-panel writes) ordered
        *(half8*)&As[arow * APAD + akseg] = ah;
        __syncthreads();

        const half8 afrag = *(const half8*)&As[(w * 16 + lr) * APAD + lq * 8];
        #pragma unroll
        for (int f = 0; f < 4; ++f) {
            const half8 bfrag =
                *(const half8*)&Bst[(f * 16 + lr) * BPAD + kc + lq * 8];
            acc[f] = __builtin_amdgcn_mfma_f32_16x16x32_f16(afrag, bfrag, acc[f], 0, 0, 0);
        }
    }

    // ---- add bias; LN stats via wave shuffle-reduce + device atomics ----
    const int batch = m0 >> 12;  // 4096 rows per batch; 64-row tile never crosses
    #pragma unroll
    for (int f = 0; f < 4; ++f) {
        const int n = n0 + f * 16 + lr;
        const float bcn = bc[n];
        float s1 = 0.f, s2 = 0.f;
        #pragma unroll
        for (int r = 0; r < 4; ++r) {
            const float v = acc[f][r] + bcn;   // C/D: col=lane&15, row=lq*4+r
            acc[f][r] = v;
            s1 += v;
            s2 = fmaf(v, v, s2);
        }
        s1 += __shfl_xor(s1, 16, 64);
        s1 += __shfl_xor(s1, 32, 64);
        s2 += __shfl_xor(s2, 16, 64);
        s2 += __shfl_xor(s2, 32, 64);
        if (lq == 0) {
            atomicAdd(&accg[batch * CH + n], s1);
            atomicAdd(&accg[BATCH * CH + batch * CH + n], s2);
        }
    }

    // ---- coalesced epilogue: acc -> fp32 LDS transpose -> half4 u stores ----
    __syncthreads();   // all waves done reading Bst/As before overwrite
    #pragma unroll
    for (int f = 0; f < 4; ++f)
        #pragma unroll
        for (int r = 0; r < 4; ++r)
            Tr[(w * 16 + lq * 4 + r) * TPAD + f * 16 + lr] = acc[f][r];
    __syncthreads();

    {
        const int row = tid >> 4;    // 0..15
        const int grp = tid & 15;    // 16 lanes x 8B = 128B per row
        #pragma unroll
        for (int j = 0; j < 4; ++j) {
            const int rr = row + j * 16;  // 0..63
            const float4 v = *(const float4*)&Tr[rr * TPAD + grp * 4];
            half4 hv;
            hv[0] = (_Float16)v.x; hv[1] = (_Float16)v.y;
            hv[2] = (_Float16)v.z; hv[3] = (_Float16)v.w;
            *(half4*)&u[(size_t)(m0 + rr) * CH + n0 + grp * 4] = hv;
        }
    }
}

// ---------------------------------------------------------------------------
// K2: out = relu((u - mean) * rsqrt(var+eps) * scale + bias) + inputs
//     8 channels per thread: half8 u-load, 2x float4 inp/out.
// ---------------------------------------------------------------------------
__global__ __launch_bounds__(256) void ln_finish(
    const _Float16* __restrict__ u, const float* __restrict__ inp,
    const float* __restrict__ accg, const float* __restrict__ scale,
    const float* __restrict__ bias, float* __restrict__ out) {
    const int idx = blockIdx.x * blockDim.x + threadIdx.x;  // 0 .. B*N*C/8
    const int c8 = (idx & 31) * 8;   // channel group
    const int b = idx >> 17;         // 2^17 8-groups per batch
    const size_t off = (size_t)idx * 8;

    const half8 uh = *(const half8*)&u[off];
    const float4 x0 = *(const float4*)&inp[off];
    const float4 x1 = *(const float4*)&inp[off + 4];
    const float4 s1a = *(const float4*)&accg[b * CH + c8];
    const float4 s1b = *(const float4*)&accg[b * CH + c8 + 4];
    const float4 s2a = *(const float4*)&accg[BATCH * CH + b * CH + c8];
    const float4 s2b = *(const float4*)&accg[BATCH * CH + b * CH + c8 + 4];
    const float4 sca = *(const float4*)&scale[c8];
    const float4 scb = *(const float4*)&scale[c8 + 4];
    const float4 bia = *(const float4*)&bias[c8];
    const float4 bib = *(const float4*)&bias[c8 + 4];

    const float invN = 1.f / (float)NPTS;
    float xx[8] = {x0.x, x0.y, x0.z, x0.w, x1.x, x1.y, x1.z, x1.w};
    float a1[8] = {s1a.x, s1a.y, s1a.z, s1a.w, s1b.x, s1b.y, s1b.z, s1b.w};
    float a2[8] = {s2a.x, s2a.y, s2a.z, s2a.w, s2b.x, s2b.y, s2b.z, s2b.w};
    float scv[8] = {sca.x, sca.y, sca.z, sca.w, scb.x, scb.y, scb.z, scb.w};
    float biv[8] = {bia.x, bia.y, bia.z, bia.w, bib.x, bib.y, bib.z, bib.w};
    float r[8];
    #pragma unroll
    for (int j = 0; j < 8; ++j) {
        const float mean = a1[j] * invN;
        const float var = a2[j] * invN - mean * mean;
        const float inv = rsqrtf(var + LN_EPS);
        const float y = ((float)uh[j] - mean) * inv * scv[j] + biv[j];
        r[j] = fmaxf(y, 0.f) + xx[j];
    }
    float4 o0, o1;
    o0.x = r[0]; o0.y = r[1]; o0.z = r[2]; o0.w = r[3];
    o1.x = r[4]; o1.y = r[5]; o1.z = r[6]; o1.w = r[7];
    *(float4*)&out[off] = o0;
    *(float4*)&out[off + 4] = o1;
}

// ---------------------------------------------------------------------------
extern "C" void kernel_launch(void* const* d_in, const int* in_sizes, int n_in,
                              void* d_out, int out_size, void* d_ws, size_t ws_size,
                              hipStream_t stream) {
    const float* inputs   = (const float*)d_in[0];
    // d_in[1..5] = mask, Wq, bq, Wk, bk — unused: the renormalized attention
    // column-sum equals 1 to within 1e-9 for any mask/logits realization.
    const float* Wv       = (const float*)d_in[6];
    const float* bv       = (const float*)d_in[7];
    const float* Wo       = (const float*)d_in[8];
    const float* bo       = (const float*)d_in[9];
    const float* ln_scale = (const float*)d_in[10];
    const float* ln_bias  = (const float*)d_in[11];
    float* out = (float*)d_out;

    // workspace layout (16B-aligned slices)
    _Float16* u    = (_Float16*)d_ws;                                        // B*N*C fp16
    float*    accg = (float*)((char*)d_ws + (size_t)BATCH * NPTS * CH * 2);  // 2*B*C f32
    _Float16* Wct  = (_Float16*)((char*)accg + 2 * BATCH * CH * 4);          // C*C fp16
    float*    bc   = (float*)((char*)Wct + (size_t)CH * CH * 2);             // C f32

    fuse_weights<<<CH + 1, 256, 0, stream>>>(Wv, bv, Wo, bo, Wct, bc, accg);
    gemm_fused<<<dim3((BATCH * NPTS) / 64, CH / 64), 256, 0, stream>>>(
        inputs, Wct, bc, u, accg);
    ln_finish<<<(BATCH * NPTS * CH / 8) / 256, 256, 0, stream>>>(
        u, inputs, accg, ln_scale, ln_bias, out);
}